// Round 14
// baseline (206.791 us; speedup 1.0000x reference)
//
#include <hip/hip_runtime.h>
#include <hip/hip_bf16.h>
#include <math.h>

#define NN 20000
#define DEGV 16
#define CINV 128
#define TSTEPS 3
#define HIDV 128

typedef float f32x4 __attribute__((ext_vector_type(4)));
typedef short s16x8 __attribute__((ext_vector_type(8)));

#define MFMA16(a, b, c) __builtin_amdgcn_mfma_f32_16x16x32_bf16(a, b, c, 0, 0, 0)

static __device__ __forceinline__ short f2bf(float x) {
    __hip_bfloat16 h = __float2bfloat16(x);
    return *reinterpret_cast<short*>(&h);
}

// fast f64 exp (rel err ~1e-13)
static __device__ __forceinline__ double exp_fast(double x) {
    const double LOG2E = 1.4426950408889634074;
    const double LN2HI = 6.93147180369123816490e-01;
    const double LN2LO = 1.90821492927058770002e-10;
    double fn = floor(fma(x, LOG2E, 0.5));
    double r  = fma(fn, -LN2HI, x);
    r = fma(fn, -LN2LO, r);
    double p = 2.08767569878680989792e-09;
    p = fma(p, r, 2.50521083854417187751e-08);
    p = fma(p, r, 2.75573192239858906526e-07);
    p = fma(p, r, 2.75573192239858925110e-06);
    p = fma(p, r, 2.48015873015873015873e-05);
    p = fma(p, r, 1.98412698412698412526e-04);
    p = fma(p, r, 1.38888888888888894568e-03);
    p = fma(p, r, 8.33333333333333321769e-03);
    p = fma(p, r, 4.16666666666666643537e-02);
    p = fma(p, r, 1.66666666666666657415e-01);
    p = fma(p, r, 5.0e-01);
    p = fma(p, r, 1.0);
    p = fma(p, r, 1.0);
    long long bits = __double_as_longlong(p) + ((long long)(int)fn << 52);
    return __longlong_as_double(bits);
}

// ---------------------------------------------------------------------------
// Kernel 1: P[s][n][j] (slot-major), base, walk_idx[0], vb. Unchanged.
// ---------------------------------------------------------------------------
__global__ __launch_bounds__(256) void k_precompute(
    const float* __restrict__ v, const float* __restrict__ W1,
    const float* __restrict__ b1,
    float* __restrict__ P, float* __restrict__ base, int* __restrict__ walk_idx,
    short* __restrict__ vb)
{
    __shared__ float vt[32][132];
    int nb = blockIdx.x * 32;
    for (int idx = threadIdx.x; idx < 32 * 128; idx += 256) {
        int nl = idx >> 7, k = idx & 127;
        float x = v[(size_t)(nb + nl) * 128 + k];
        int k4 = (k >> 2) ^ (nl >> 3);
        vt[nl][(k4 << 2) | (k & 3)] = x;
        vb[(size_t)(nb + nl) * 128 + k] = f2bf(x);
    }
    __syncthreads();

    int s  = threadIdx.x >> 6;
    int jg = (threadIdx.x >> 2) & 15;
    int ng = threadIdx.x & 3;

    double accd[8][4];
#pragma unroll
    for (int i = 0; i < 8; ++i)
#pragma unroll
        for (int m = 0; m < 4; ++m) accd[i][m] = 0.0;

    const float* w1s = W1 + (size_t)s * 128 * 64 + jg;

    for (int kb = 0; kb < 8; ++kb) {
        float acc[8][4];
#pragma unroll
        for (int i = 0; i < 8; ++i)
#pragma unroll
            for (int m = 0; m < 4; ++m) acc[i][m] = 0.f;
#pragma unroll
        for (int kq = 0; kq < 4; ++kq) {
            int K4 = kb * 4 + kq;
            float4 xv[8];
#pragma unroll
            for (int i = 0; i < 8; ++i)
                xv[i] = *(const float4*)&vt[ng * 8 + i][(K4 ^ ng) << 2];
#pragma unroll
            for (int kk = 0; kk < 4; ++kk) {
                int k = K4 * 4 + kk;
                float w0 = w1s[k * 64 +  0];
                float w1 = w1s[k * 64 + 16];
                float w2 = w1s[k * 64 + 32];
                float w3 = w1s[k * 64 + 48];
#pragma unroll
                for (int i = 0; i < 8; ++i) {
                    float x = (kk == 0) ? xv[i].x : (kk == 1) ? xv[i].y
                            : (kk == 2) ? xv[i].z : xv[i].w;
                    acc[i][0] = fmaf(x, w0, acc[i][0]);
                    acc[i][1] = fmaf(x, w1, acc[i][1]);
                    acc[i][2] = fmaf(x, w2, acc[i][2]);
                    acc[i][3] = fmaf(x, w3, acc[i][3]);
                }
            }
        }
#pragma unroll
        for (int i = 0; i < 8; ++i)
#pragma unroll
            for (int m = 0; m < 4; ++m) accd[i][m] += (double)acc[i][m];
    }

#pragma unroll
    for (int i = 0; i < 8; ++i) {
        int n = nb + ng * 8 + i;
#pragma unroll
        for (int m = 0; m < 4; ++m) {
            int j = jg + 16 * m;
            float pv = (float)accd[i][m];
            P[(size_t)s * NN * 64 + (size_t)n * 64 + j] = pv;
            if (s == 0) {
                base[(size_t)n * 64 + j] = pv + b1[j];
                if (j == 0) walk_idx[n] = n;
            }
        }
    }
}

// ---------------------------------------------------------------------------
// Kernel 2: all 3 walk steps fused (unchanged from r13, passed 0.0039)
// ---------------------------------------------------------------------------
__global__ __launch_bounds__(256) void k_walk_fused(
    const float* __restrict__ P, const float* __restrict__ base_g,
    const int* __restrict__ dst, const float* __restrict__ W2,
    const float* __restrict__ b2, const float* __restrict__ noise,
    int* __restrict__ walk_idx)
{
    int wave = threadIdx.x >> 6;
    int lane = threadIdx.x & 63;
    int n = blockIdx.x * 4 + wave;
    int d = lane >> 2, sub = lane & 3;

    float4 base_r[4], w2r[4];
    {
        const float4* bg = (const float4*)(base_g + (size_t)n * 64 + sub * 16);
        const float4* wg = ((const float4*)W2) + sub * 4;
#pragma unroll
        for (int k = 0; k < 4; ++k) { base_r[k] = bg[k]; w2r[k] = wg[k]; }
    }
    double b2d = (double)b2[0];

    int wl = n;
#pragma unroll 1
    for (int t = 0; t < TSTEPS; ++t) {
        const float* Pslice = P + (size_t)(t + 1) * NN * 64;
        int cand = dst[wl * DEGV + d];
        const float4* p4 = (const float4*)(Pslice + (size_t)cand * 64 + sub * 16);

        float4 pp_s[4];
        double acc = 0.0;
#pragma unroll
        for (int k = 0; k < 4; ++k) {
            float4 bb = base_r[k];
            float4 pp = p4[k];
            pp_s[k] = pp;
            float4 ww = w2r[k];
            acc += (double)fmaxf(bb.x + pp.x, 0.f) * (double)ww.x;
            acc += (double)fmaxf(bb.y + pp.y, 0.f) * (double)ww.y;
            acc += (double)fmaxf(bb.z + pp.z, 0.f) * (double)ww.z;
            acc += (double)fmaxf(bb.w + pp.w, 0.f) * (double)ww.w;
        }
        acc += __shfl_xor(acc, 1);
        acc += __shfl_xor(acc, 2);
        double logp = acc + b2d;

        double m = logp;
        for (int mask = 4; mask < 64; mask <<= 1) m = fmax(m, __shfl_xor(m, mask));
        double e = exp_fast(logp - m);
        double ssum = e;
        for (int mask = 4; mask < 64; mask <<= 1) ssum += __shfl_xor(ssum, mask);

        double wp = e / ssum +
                    0.01 * (double)noise[((size_t)t * NN + n) * DEGV + d];

        int bd = d;
        double bwp = wp;
        for (int mask = 4; mask < 64; mask <<= 1) {
            double owp = __shfl_xor(bwp, mask);
            int od = __shfl_xor(bd, mask);
            if (owp > bwp || (owp == bwp && od < bd)) { bwp = owp; bd = od; }
        }
        int sel = dst[wl * DEGV + bd];

        int srcl = bd * 4 + sub;
#pragma unroll
        for (int k = 0; k < 4; ++k) {
            base_r[k].x += __shfl(pp_s[k].x, srcl);
            base_r[k].y += __shfl(pp_s[k].y, srcl);
            base_r[k].z += __shfl(pp_s[k].z, srcl);
            base_r[k].w += __shfl(pp_s[k].w, srcl);
        }
        if (lane == 0) walk_idx[(t + 1) * NN + n] = sel;
        wl = sel;
    }
}

// ---------------------------------------------------------------------------
// Kernel 3: convert weights to bf16 (unchanged)
// ---------------------------------------------------------------------------
__global__ __launch_bounds__(256) void k_convert_w(
    const float* __restrict__ Wih, const float* __restrict__ Whh,
    const float* __restrict__ Wout,
    short* __restrict__ Wihb, short* __restrict__ Whhb, short* __restrict__ WoutTb)
{
    int idx = blockIdx.x * 256 + threadIdx.x;
    if (idx < 49152) {
        Wihb[idx] = f2bf(Wih[idx]);
    } else if (idx < 98304) {
        int e = idx - 49152;
        Whhb[e] = f2bf(Whh[e]);
    } else if (idx < 114688) {
        int e = idx - 98304;
        int o = e >> 7, k = e & 127;
        WoutTb[e] = f2bf(Wout[k * 128 + o]);   // WoutT[o][k]
    }
}

// ---------------------------------------------------------------------------
// Kernel 4: fused GRU + out-proj — BARRIER-FREE single-wave blocks.
// Block = 64 threads (1 wave), 32 nodes (2 A-groups sharing B-frags).
// Grid = 625. Wave owns ALL 8 u-slices, slice-sequential (unroll 1) to
// bound registers. h in wave-private LDS (no cross-wave exchange -> the
// __syncthreads is a single-wave no-op). x A-frags loaded DIRECTLY from
// global (vb row-major, 16B per lane). h_prev carried as bf16 (same value
// MFMA consumes). No wave ever waits on another wave.
// A-frag: row=lane&15, k=(lane>>4)*8. C/D: row=(lane>>4)*4+i, col=lane&15.
// ---------------------------------------------------------------------------
__global__ __launch_bounds__(64) void k_gru_fused(
    const short* __restrict__ vb, const int* __restrict__ widx,
    const short* __restrict__ Wihb, const short* __restrict__ Whhb,
    const short* __restrict__ WoutTb,
    const float* __restrict__ bih, const float* __restrict__ bhh,
    const float* __restrict__ bout, float* __restrict__ out)
{
    __shared__ short h_lds[32][136];
    int lane = threadIdx.x;
    int c = lane & 15, q = lane >> 4;
    int nb = blockIdx.x * 32;

#pragma unroll 1
    for (int t = 0; t < 1 + TSTEPS; ++t) {
        int src0 = widx[t * NN + nb + c];
        int src1 = widx[t * NN + nb + 16 + c];

        s16x8 ax[2][4];
#pragma unroll
        for (int ks = 0; ks < 4; ++ks) {
            ax[0][ks] = *(const s16x8*)(vb + (size_t)src0 * 128 + ks * 32 + q * 8);
            ax[1][ks] = *(const s16x8*)(vb + (size_t)src1 * 128 + ks * 32 + q * 8);
        }
        s16x8 ah[2][4];
        if (t > 0) {
#pragma unroll
            for (int g = 0; g < 2; ++g)
#pragma unroll
                for (int ks = 0; ks < 4; ++ks)
                    ah[g][ks] = *(const s16x8*)&h_lds[g * 16 + c][ks * 32 + q * 8];
        }

#pragma unroll 1
        for (int sl = 0; sl < 8; ++sl) {
            const short* bi = Wihb + c * 128 + q * 8 + sl * 2048;
            const short* bh = Whhb + c * 128 + q * 8 + sl * 2048;
            f32x4 zf = {0.f, 0.f, 0.f, 0.f};
            f32x4 aR[2] = {zf, zf}, aZ[2] = {zf, zf}, aIN[2] = {zf, zf}, aHN[2] = {zf, zf};
#pragma unroll
            for (int ks = 0; ks < 4; ++ks) {
                s16x8 wiR = *(const s16x8*)(bi + ks * 32);
                s16x8 wiZ = *(const s16x8*)(bi + 8 * 2048 + ks * 32);
                s16x8 wiN = *(const s16x8*)(bi + 16 * 2048 + ks * 32);
#pragma unroll
                for (int g = 0; g < 2; ++g) {
                    aR[g]  = MFMA16(ax[g][ks], wiR, aR[g]);
                    aZ[g]  = MFMA16(ax[g][ks], wiZ, aZ[g]);
                    aIN[g] = MFMA16(ax[g][ks], wiN, aIN[g]);
                }
            }
            if (t > 0) {
#pragma unroll
                for (int ks = 0; ks < 4; ++ks) {
                    s16x8 whR = *(const s16x8*)(bh + ks * 32);
                    s16x8 whZ = *(const s16x8*)(bh + 8 * 2048 + ks * 32);
                    s16x8 whN = *(const s16x8*)(bh + 16 * 2048 + ks * 32);
#pragma unroll
                    for (int g = 0; g < 2; ++g) {
                        aR[g]  = MFMA16(ah[g][ks], whR, aR[g]);
                        aZ[g]  = MFMA16(ah[g][ks], whZ, aZ[g]);
                        aHN[g] = MFMA16(ah[g][ks], whN, aHN[g]);
                    }
                }
            }
            int u = sl * 16 + c;
            float b_r  = bih[u] + bhh[u];
            float b_z  = bih[128 + u] + bhh[128 + u];
            float b_in = bih[256 + u];
            float b_hn = bhh[256 + u];
#pragma unroll
            for (int g = 0; g < 2; ++g)
#pragma unroll
                for (int i = 0; i < 4; ++i) {
                    float r = 1.f / (1.f + __expf(-(aR[g][i] + b_r)));
                    float z = 1.f / (1.f + __expf(-(aZ[g][i] + b_z)));
                    float narg = aIN[g][i] + b_in + r * (aHN[g][i] + b_hn);
                    float e2 = __expf(2.f * narg);
                    float ngt = 1.f - 2.f / (e2 + 1.f);
                    float hprev = 0.f;
                    if (t > 0) {
                        unsigned short hb =
                            *(const unsigned short*)&h_lds[g * 16 + q * 4 + i][u];
                        hprev = __uint_as_float(((unsigned)hb) << 16);
                    }
                    float hn = (1.f - z) * ngt + z * hprev;
                    h_lds[g * 16 + q * 4 + i][u] = f2bf(hn);
                }
        }
        __syncthreads();   // single-wave: compiles to a cheap waitcnt fence
    }

    // ---- output projection ----
    s16x8 ah[2][4];
#pragma unroll
    for (int g = 0; g < 2; ++g)
#pragma unroll
        for (int ks = 0; ks < 4; ++ks)
            ah[g][ks] = *(const s16x8*)&h_lds[g * 16 + c][ks * 32 + q * 8];

#pragma unroll 1
    for (int sl = 0; sl < 8; ++sl) {
        const short* bo = WoutTb + c * 128 + q * 8 + sl * 2048;
        f32x4 zf = {0.f, 0.f, 0.f, 0.f};
        f32x4 acco[2] = {zf, zf};
#pragma unroll
        for (int ks = 0; ks < 4; ++ks) {
            s16x8 w = *(const s16x8*)(bo + ks * 32);
#pragma unroll
            for (int g = 0; g < 2; ++g)
                acco[g] = MFMA16(ah[g][ks], w, acco[g]);
        }
        int o = sl * 16 + c;
        float bb = bout[o];
#pragma unroll
        for (int g = 0; g < 2; ++g)
#pragma unroll
            for (int i = 0; i < 4; ++i)
                out[(size_t)(nb + g * 16 + q * 4 + i) * 128 + o] = acco[g][i] + bb;
    }
}

// ---------------------------------------------------------------------------
extern "C" void kernel_launch(void* const* d_in, const int* in_sizes, int n_in,
                              void* d_out, int out_size, void* d_ws, size_t ws_size,
                              hipStream_t stream)
{
    const float* node_attr = (const float*)d_in[0];
    const int*   edge_index = (const int*)d_in[1];
    const float* W1  = (const float*)d_in[3];
    const float* b1  = (const float*)d_in[4];
    const float* W2  = (const float*)d_in[5];
    const float* b2  = (const float*)d_in[6];
    const float* Wih = (const float*)d_in[7];
    const float* Whh = (const float*)d_in[8];
    const float* bih = (const float*)d_in[9];
    const float* bhh = (const float*)d_in[10];
    const float* Wout = (const float*)d_in[11];
    const float* bout = (const float*)d_in[12];
    const float* noise = (const float*)d_in[13];

    const int* dst = edge_index + (size_t)NN * DEGV;

    char* ws = (char*)d_ws;
    size_t offP    = 0;                               // 4*N*64 f32 = 20.48 MB
    size_t offBase = offP + (size_t)4 * NN * 64 * 4;  // N*64 f32   =  5.12 MB
    size_t offW    = offBase + (size_t)NN * 64 * 4;   // bf16 weights 0.23 MB
    size_t offWidx = offW + (size_t)(2 * 49152 + 16384) * 2;
    size_t offVb   = offWidx + (size_t)4 * NN * 4;    // bf16 v = 5.12 MB
    float* P    = (float*)(ws + offP);
    float* base = (float*)(ws + offBase);
    short* Wihb   = (short*)(ws + offW);
    short* Whhb   = Wihb + 384 * 128;
    short* WoutTb = Whhb + 384 * 128;
    int*   widx = (int*)(ws + offWidx);
    short* vb   = (short*)(ws + offVb);

    dim3 blk(256);
    k_convert_w<<<dim3(448), blk, 0, stream>>>(Wih, Whh, Wout, Wihb, Whhb, WoutTb);
    k_precompute<<<dim3(625), blk, 0, stream>>>(node_attr, W1, b1, P, base, widx, vb);
    k_walk_fused<<<dim3(5000), blk, 0, stream>>>(P, base, dst, W2, b2, noise, widx);
    k_gru_fused<<<dim3(625), dim3(64), 0, stream>>>(vb, widx, Wihb, Whhb, WoutTb,
                                                    bih, bhh, bout, (float*)d_out);
}

// Round 15
// 185.578 us; speedup vs baseline: 1.1143x; 1.1143x over previous
//
#include <hip/hip_runtime.h>
#include <hip/hip_bf16.h>
#include <math.h>

#define NN 20000
#define DEGV 16
#define CINV 128
#define TSTEPS 3
#define HIDV 128

typedef float f32x4 __attribute__((ext_vector_type(4)));
typedef short s16x8 __attribute__((ext_vector_type(8)));

#define MFMA16(a, b, c) __builtin_amdgcn_mfma_f32_16x16x32_bf16(a, b, c, 0, 0, 0)

static __device__ __forceinline__ short f2bf(float x) {
    __hip_bfloat16 h = __float2bfloat16(x);
    return *reinterpret_cast<short*>(&h);
}

// fast f64 exp (rel err ~1e-13)
static __device__ __forceinline__ double exp_fast(double x) {
    const double LOG2E = 1.4426950408889634074;
    const double LN2HI = 6.93147180369123816490e-01;
    const double LN2LO = 1.90821492927058770002e-10;
    double fn = floor(fma(x, LOG2E, 0.5));
    double r  = fma(fn, -LN2HI, x);
    r = fma(fn, -LN2LO, r);
    double p = 2.08767569878680989792e-09;
    p = fma(p, r, 2.50521083854417187751e-08);
    p = fma(p, r, 2.75573192239858906526e-07);
    p = fma(p, r, 2.75573192239858925110e-06);
    p = fma(p, r, 2.48015873015873015873e-05);
    p = fma(p, r, 1.98412698412698412526e-04);
    p = fma(p, r, 1.38888888888888894568e-03);
    p = fma(p, r, 8.33333333333333321769e-03);
    p = fma(p, r, 4.16666666666666643537e-02);
    p = fma(p, r, 1.66666666666666657415e-01);
    p = fma(p, r, 5.0e-01);
    p = fma(p, r, 1.0);
    p = fma(p, r, 1.0);
    long long bits = __double_as_longlong(p) + ((long long)(int)fn << 52);
    return __longlong_as_double(bits);
}

// ---------------------------------------------------------------------------
// Kernel 1: P[s][n][j] (slot-major), base, walk_idx[0], vb (bf16 v),
// PLUS folded-in weight conversion (Wih/Whh bf16, Wout transposed bf16) —
// grid 625 x 256 = 160000 threads >= 114688 elements, <=1 elem/thread.
// Main GEMM path unchanged from r12 (FMA order bit-identical).
// ---------------------------------------------------------------------------
__global__ __launch_bounds__(256) void k_precompute(
    const float* __restrict__ v, const float* __restrict__ W1,
    const float* __restrict__ b1,
    const float* __restrict__ Wih, const float* __restrict__ Whh,
    const float* __restrict__ Wout,
    float* __restrict__ P, float* __restrict__ base, int* __restrict__ walk_idx,
    short* __restrict__ vb,
    short* __restrict__ Wihb, short* __restrict__ Whhb, short* __restrict__ WoutTb)
{
    // folded weight conversion (independent of everything below)
    {
        int idx = blockIdx.x * 256 + threadIdx.x;
        if (idx < 49152) {
            Wihb[idx] = f2bf(Wih[idx]);
        } else if (idx < 98304) {
            int e = idx - 49152;
            Whhb[e] = f2bf(Whh[e]);
        } else if (idx < 114688) {
            int e = idx - 98304;
            int o = e >> 7, k = e & 127;
            WoutTb[e] = f2bf(Wout[k * 128 + o]);   // WoutT[o][k]
        }
    }

    __shared__ float vt[32][132];
    int nb = blockIdx.x * 32;
    for (int idx = threadIdx.x; idx < 32 * 128; idx += 256) {
        int nl = idx >> 7, k = idx & 127;
        float x = v[(size_t)(nb + nl) * 128 + k];
        int k4 = (k >> 2) ^ (nl >> 3);
        vt[nl][(k4 << 2) | (k & 3)] = x;
        vb[(size_t)(nb + nl) * 128 + k] = f2bf(x);
    }
    __syncthreads();

    int s  = threadIdx.x >> 6;
    int jg = (threadIdx.x >> 2) & 15;
    int ng = threadIdx.x & 3;

    double accd[8][4];
#pragma unroll
    for (int i = 0; i < 8; ++i)
#pragma unroll
        for (int m = 0; m < 4; ++m) accd[i][m] = 0.0;

    const float* w1s = W1 + (size_t)s * 128 * 64 + jg;

    for (int kb = 0; kb < 8; ++kb) {
        float acc[8][4];
#pragma unroll
        for (int i = 0; i < 8; ++i)
#pragma unroll
            for (int m = 0; m < 4; ++m) acc[i][m] = 0.f;
#pragma unroll
        for (int kq = 0; kq < 4; ++kq) {
            int K4 = kb * 4 + kq;
            float4 xv[8];
#pragma unroll
            for (int i = 0; i < 8; ++i)
                xv[i] = *(const float4*)&vt[ng * 8 + i][(K4 ^ ng) << 2];
#pragma unroll
            for (int kk = 0; kk < 4; ++kk) {
                int k = K4 * 4 + kk;
                float w0 = w1s[k * 64 +  0];
                float w1 = w1s[k * 64 + 16];
                float w2 = w1s[k * 64 + 32];
                float w3 = w1s[k * 64 + 48];
#pragma unroll
                for (int i = 0; i < 8; ++i) {
                    float x = (kk == 0) ? xv[i].x : (kk == 1) ? xv[i].y
                            : (kk == 2) ? xv[i].z : xv[i].w;
                    acc[i][0] = fmaf(x, w0, acc[i][0]);
                    acc[i][1] = fmaf(x, w1, acc[i][1]);
                    acc[i][2] = fmaf(x, w2, acc[i][2]);
                    acc[i][3] = fmaf(x, w3, acc[i][3]);
                }
            }
        }
#pragma unroll
        for (int i = 0; i < 8; ++i)
#pragma unroll
            for (int m = 0; m < 4; ++m) accd[i][m] += (double)acc[i][m];
    }

#pragma unroll
    for (int i = 0; i < 8; ++i) {
        int n = nb + ng * 8 + i;
#pragma unroll
        for (int m = 0; m < 4; ++m) {
            int j = jg + 16 * m;
            float pv = (float)accd[i][m];
            P[(size_t)s * NN * 64 + (size_t)n * 64 + j] = pv;
            if (s == 0) {
                base[(size_t)n * 64 + j] = pv + b1[j];
                if (j == 0) walk_idx[n] = n;
            }
        }
    }
}

// ---------------------------------------------------------------------------
// Kernel 2: all 3 walk steps fused, one wave per node. base in registers.
// P[sel] accumulated via lane-group broadcast (bit-identical values, no
// re-gather round).
// ---------------------------------------------------------------------------
__global__ __launch_bounds__(256) void k_walk_fused(
    const float* __restrict__ P, const float* __restrict__ base_g,
    const int* __restrict__ dst, const float* __restrict__ W2,
    const float* __restrict__ b2, const float* __restrict__ noise,
    int* __restrict__ walk_idx)
{
    int wave = threadIdx.x >> 6;
    int lane = threadIdx.x & 63;
    int n = blockIdx.x * 4 + wave;
    int d = lane >> 2, sub = lane & 3;

    float4 base_r[4], w2r[4];
    {
        const float4* bg = (const float4*)(base_g + (size_t)n * 64 + sub * 16);
        const float4* wg = ((const float4*)W2) + sub * 4;
#pragma unroll
        for (int k = 0; k < 4; ++k) { base_r[k] = bg[k]; w2r[k] = wg[k]; }
    }
    double b2d = (double)b2[0];

    int wl = n;
#pragma unroll 1
    for (int t = 0; t < TSTEPS; ++t) {
        const float* Pslice = P + (size_t)(t + 1) * NN * 64;
        int cand = dst[wl * DEGV + d];
        const float4* p4 = (const float4*)(Pslice + (size_t)cand * 64 + sub * 16);

        float4 pp_s[4];
        double acc = 0.0;
#pragma unroll
        for (int k = 0; k < 4; ++k) {
            float4 bb = base_r[k];
            float4 pp = p4[k];
            pp_s[k] = pp;
            float4 ww = w2r[k];
            acc += (double)fmaxf(bb.x + pp.x, 0.f) * (double)ww.x;
            acc += (double)fmaxf(bb.y + pp.y, 0.f) * (double)ww.y;
            acc += (double)fmaxf(bb.z + pp.z, 0.f) * (double)ww.z;
            acc += (double)fmaxf(bb.w + pp.w, 0.f) * (double)ww.w;
        }
        acc += __shfl_xor(acc, 1);
        acc += __shfl_xor(acc, 2);
        double logp = acc + b2d;

        double m = logp;
        for (int mask = 4; mask < 64; mask <<= 1) m = fmax(m, __shfl_xor(m, mask));
        double e = exp_fast(logp - m);
        double ssum = e;
        for (int mask = 4; mask < 64; mask <<= 1) ssum += __shfl_xor(ssum, mask);

        double wp = e / ssum +
                    0.01 * (double)noise[((size_t)t * NN + n) * DEGV + d];

        int bd = d;
        double bwp = wp;
        for (int mask = 4; mask < 64; mask <<= 1) {
            double owp = __shfl_xor(bwp, mask);
            int od = __shfl_xor(bd, mask);
            if (owp > bwp || (owp == bwp && od < bd)) { bwp = owp; bd = od; }
        }
        int sel = dst[wl * DEGV + bd];

        int srcl = bd * 4 + sub;
#pragma unroll
        for (int k = 0; k < 4; ++k) {
            base_r[k].x += __shfl(pp_s[k].x, srcl);
            base_r[k].y += __shfl(pp_s[k].y, srcl);
            base_r[k].z += __shfl(pp_s[k].z, srcl);
            base_r[k].w += __shfl(pp_s[k].w, srcl);
        }
        if (lane == 0) walk_idx[(t + 1) * NN + n] = sel;
        wl = sel;
    }
}

// ---------------------------------------------------------------------------
// Kernel 3: fused GRU (4 steps) + output projection, MFMA bf16.
// EXACT r9 structure (best measured 59.6 us), only change: launch_bounds
// (512,8) -> residency cap 4 blocks/CU so ALL 625 blocks run in ONE round
// (r9's (512,4) capped at 2/CU -> ~2.2 serial rounds of the recurrence
// critical path). Compiler already allocates exactly 64 VGPR = the (512,8)
// budget, so no spill expected.
// ---------------------------------------------------------------------------
__global__ __launch_bounds__(512, 8) void k_gru_fused(
    const short* __restrict__ vb, const int* __restrict__ widx,
    const short* __restrict__ Wihb, const short* __restrict__ Whhb,
    const short* __restrict__ WoutTb,
    const float* __restrict__ bih, const float* __restrict__ bhh,
    const float* __restrict__ bout, float* __restrict__ out)
{
    __shared__ short x_bf[32][136];
    __shared__ short h_bf[32][136];
    int tid = threadIdx.x;
    int j = tid >> 6, lane = tid & 63;
    int c = lane & 15, q = lane >> 4;
    int nb = blockIdx.x * 32;
    int u = j * 16 + c;

    float b_r  = bih[u] + bhh[u];
    float b_z  = bih[128 + u] + bhh[128 + u];
    float b_in = bih[256 + u];
    float b_hn = bhh[256 + u];

    float h_reg[2][4];
#pragma unroll
    for (int g = 0; g < 2; ++g)
#pragma unroll
        for (int i = 0; i < 4; ++i) h_reg[g][i] = 0.f;

    const short* bi_base = Wihb + c * 128 + q * 8 + j * 2048;
    const short* bh_base = Whhb + c * 128 + q * 8 + j * 2048;

#pragma unroll 1
    for (int t = 0; t < 1 + TSTEPS; ++t) {
        {
            int row = tid >> 4, chunk = tid & 15;
            int src = widx[t * NN + nb + row];
            *(s16x8*)&x_bf[row][chunk * 8] =
                *(const s16x8*)(vb + (size_t)src * 128 + chunk * 8);
        }
        __syncthreads();

        float rr[2][4], zz[2][4];

        // pass 1: r and z
        {
            f32x4 zf = {0.f, 0.f, 0.f, 0.f};
            f32x4 aR[2] = {zf, zf}, aZ[2] = {zf, zf};
#pragma unroll
            for (int ks = 0; ks < 4; ++ks) {
                s16x8 biR = *(const s16x8*)(bi_base + ks * 32);
                s16x8 biZ = *(const s16x8*)(bi_base + 8 * 2048 + ks * 32);
#pragma unroll
                for (int g = 0; g < 2; ++g) {
                    s16x8 a = *(const s16x8*)&x_bf[g * 16 + c][ks * 32 + q * 8];
                    aR[g] = MFMA16(a, biR, aR[g]);
                    aZ[g] = MFMA16(a, biZ, aZ[g]);
                }
            }
            if (t > 0) {
#pragma unroll
                for (int ks = 0; ks < 4; ++ks) {
                    s16x8 bhR = *(const s16x8*)(bh_base + ks * 32);
                    s16x8 bhZ = *(const s16x8*)(bh_base + 8 * 2048 + ks * 32);
#pragma unroll
                    for (int g = 0; g < 2; ++g) {
                        s16x8 a = *(const s16x8*)&h_bf[g * 16 + c][ks * 32 + q * 8];
                        aR[g] = MFMA16(a, bhR, aR[g]);
                        aZ[g] = MFMA16(a, bhZ, aZ[g]);
                    }
                }
            }
#pragma unroll
            for (int g = 0; g < 2; ++g)
#pragma unroll
                for (int i = 0; i < 4; ++i) {
                    rr[g][i] = 1.f / (1.f + __expf(-(aR[g][i] + b_r)));
                    zz[g][i] = 1.f / (1.f + __expf(-(aZ[g][i] + b_z)));
                }
        }

        // pass 2: in and hn, then epilogue
        {
            f32x4 zf = {0.f, 0.f, 0.f, 0.f};
            f32x4 aIN[2] = {zf, zf}, aHN[2] = {zf, zf};
#pragma unroll
            for (int ks = 0; ks < 4; ++ks) {
                s16x8 biN = *(const s16x8*)(bi_base + 16 * 2048 + ks * 32);
#pragma unroll
                for (int g = 0; g < 2; ++g) {
                    s16x8 a = *(const s16x8*)&x_bf[g * 16 + c][ks * 32 + q * 8];
                    aIN[g] = MFMA16(a, biN, aIN[g]);
                }
            }
            if (t > 0) {
#pragma unroll
                for (int ks = 0; ks < 4; ++ks) {
                    s16x8 bhN = *(const s16x8*)(bh_base + 16 * 2048 + ks * 32);
#pragma unroll
                    for (int g = 0; g < 2; ++g) {
                        s16x8 a = *(const s16x8*)&h_bf[g * 16 + c][ks * 32 + q * 8];
                        aHN[g] = MFMA16(a, bhN, aHN[g]);
                    }
                }
            }
            __syncthreads();
#pragma unroll
            for (int g = 0; g < 2; ++g)
#pragma unroll
                for (int i = 0; i < 4; ++i) {
                    float narg = aIN[g][i] + b_in + rr[g][i] * (aHN[g][i] + b_hn);
                    float e2 = __expf(2.f * narg);
                    float ngt = 1.f - 2.f / (e2 + 1.f);
                    float hn = (1.f - zz[g][i]) * ngt + zz[g][i] * h_reg[g][i];
                    h_reg[g][i] = hn;
                    h_bf[g * 16 + q * 4 + i][u] = f2bf(hn);
                }
        }
        __syncthreads();
    }

    // output projection
    {
        const short* bo_base = WoutTb + c * 128 + q * 8 + j * 2048;
        f32x4 zf = {0.f, 0.f, 0.f, 0.f};
        f32x4 acco[2] = {zf, zf};
#pragma unroll
        for (int ks = 0; ks < 4; ++ks) {
            s16x8 bo = *(const s16x8*)(bo_base + ks * 32);
#pragma unroll
            for (int g = 0; g < 2; ++g) {
                s16x8 a = *(const s16x8*)&h_bf[g * 16 + c][ks * 32 + q * 8];
                acco[g] = MFMA16(a, bo, acco[g]);
            }
        }
        float bb = bout[u];
#pragma unroll
        for (int g = 0; g < 2; ++g)
#pragma unroll
            for (int i = 0; i < 4; ++i)
                out[(size_t)(nb + g * 16 + q * 4 + i) * 128 + u] = acco[g][i] + bb;
    }
}

// ---------------------------------------------------------------------------
extern "C" void kernel_launch(void* const* d_in, const int* in_sizes, int n_in,
                              void* d_out, int out_size, void* d_ws, size_t ws_size,
                              hipStream_t stream)
{
    const float* node_attr = (const float*)d_in[0];
    const int*   edge_index = (const int*)d_in[1];
    const float* W1  = (const float*)d_in[3];
    const float* b1  = (const float*)d_in[4];
    const float* W2  = (const float*)d_in[5];
    const float* b2  = (const float*)d_in[6];
    const float* Wih = (const float*)d_in[7];
    const float* Whh = (const float*)d_in[8];
    const float* bih = (const float*)d_in[9];
    const float* bhh = (const float*)d_in[10];
    const float* Wout = (const float*)d_in[11];
    const float* bout = (const float*)d_in[12];
    const float* noise = (const float*)d_in[13];

    const int* dst = edge_index + (size_t)NN * DEGV;

    char* ws = (char*)d_ws;
    size_t offP    = 0;                               // 4*N*64 f32 = 20.48 MB
    size_t offBase = offP + (size_t)4 * NN * 64 * 4;  // N*64 f32   =  5.12 MB
    size_t offW    = offBase + (size_t)NN * 64 * 4;   // bf16 weights 0.23 MB
    size_t offWidx = offW + (size_t)(2 * 49152 + 16384) * 2;
    size_t offVb   = offWidx + (size_t)4 * NN * 4;    // bf16 v = 5.12 MB
    float* P    = (float*)(ws + offP);
    float* base = (float*)(ws + offBase);
    short* Wihb   = (short*)(ws + offW);
    short* Whhb   = Wihb + 384 * 128;
    short* WoutTb = Whhb + 384 * 128;
    int*   widx = (int*)(ws + offWidx);
    short* vb   = (short*)(ws + offVb);

    dim3 blk(256);
    k_precompute<<<dim3(625), blk, 0, stream>>>(node_attr, W1, b1, Wih, Whh, Wout,
                                                P, base, widx, vb, Wihb, Whhb, WoutTb);
    k_walk_fused<<<dim3(5000), blk, 0, stream>>>(P, base, dst, W2, b2, noise, widx);
    k_gru_fused<<<dim3(625), dim3(512), 0, stream>>>(vb, widx, Wihb, Whhb, WoutTb,
                                                     bih, bhh, bout, (float*)d_out);
}

// Round 16
// 145.766 us; speedup vs baseline: 1.4186x; 1.2731x over previous
//
#include <hip/hip_runtime.h>
#include <hip/hip_bf16.h>
#include <math.h>

#define NN 20000
#define DEGV 16
#define CINV 128
#define TSTEPS 3
#define HIDV 128

typedef float f32x4 __attribute__((ext_vector_type(4)));
typedef short s16x8 __attribute__((ext_vector_type(8)));

#define MFMA16(a, b, c) __builtin_amdgcn_mfma_f32_16x16x32_bf16(a, b, c, 0, 0, 0)

static __device__ __forceinline__ short f2bf(float x) {
    __hip_bfloat16 h = __float2bfloat16(x);
    return *reinterpret_cast<short*>(&h);
}

// fast f64 exp (rel err ~1e-13)
static __device__ __forceinline__ double exp_fast(double x) {
    const double LOG2E = 1.4426950408889634074;
    const double LN2HI = 6.93147180369123816490e-01;
    const double LN2LO = 1.90821492927058770002e-10;
    double fn = floor(fma(x, LOG2E, 0.5));
    double r  = fma(fn, -LN2HI, x);
    r = fma(fn, -LN2LO, r);
    double p = 2.08767569878680989792e-09;
    p = fma(p, r, 2.50521083854417187751e-08);
    p = fma(p, r, 2.75573192239858906526e-07);
    p = fma(p, r, 2.75573192239858925110e-06);
    p = fma(p, r, 2.48015873015873015873e-05);
    p = fma(p, r, 1.98412698412698412526e-04);
    p = fma(p, r, 1.38888888888888894568e-03);
    p = fma(p, r, 8.33333333333333321769e-03);
    p = fma(p, r, 4.16666666666666643537e-02);
    p = fma(p, r, 1.66666666666666657415e-01);
    p = fma(p, r, 5.0e-01);
    p = fma(p, r, 1.0);
    p = fma(p, r, 1.0);
    long long bits = __double_as_longlong(p) + ((long long)(int)fn << 52);
    return __longlong_as_double(bits);
}

// ---------------------------------------------------------------------------
// Kernel 1: P[s][n][j] (slot-major), base, walk_idx[0], vb (bf16 v),
// plus folded-in weight conversion. Main GEMM path FMA-order-identical
// to r12 (selections verified 8/8 runs).
// ---------------------------------------------------------------------------
__global__ __launch_bounds__(256) void k_precompute(
    const float* __restrict__ v, const float* __restrict__ W1,
    const float* __restrict__ b1,
    const float* __restrict__ Wih, const float* __restrict__ Whh,
    const float* __restrict__ Wout,
    float* __restrict__ P, float* __restrict__ base, int* __restrict__ walk_idx,
    short* __restrict__ vb,
    short* __restrict__ Wihb, short* __restrict__ Whhb, short* __restrict__ WoutTb)
{
    // folded weight conversion (grid 625*256 = 160000 threads >= 114688 elems)
    {
        int idx = blockIdx.x * 256 + threadIdx.x;
        if (idx < 49152) {
            Wihb[idx] = f2bf(Wih[idx]);
        } else if (idx < 98304) {
            int e = idx - 49152;
            Whhb[e] = f2bf(Whh[e]);
        } else if (idx < 114688) {
            int e = idx - 98304;
            int o = e >> 7, k = e & 127;
            WoutTb[e] = f2bf(Wout[k * 128 + o]);   // WoutT[o][k]
        }
    }

    __shared__ float vt[32][132];
    int nb = blockIdx.x * 32;
    for (int idx = threadIdx.x; idx < 32 * 128; idx += 256) {
        int nl = idx >> 7, k = idx & 127;
        float x = v[(size_t)(nb + nl) * 128 + k];
        int k4 = (k >> 2) ^ (nl >> 3);
        vt[nl][(k4 << 2) | (k & 3)] = x;
        vb[(size_t)(nb + nl) * 128 + k] = f2bf(x);
    }
    __syncthreads();

    int s  = threadIdx.x >> 6;
    int jg = (threadIdx.x >> 2) & 15;
    int ng = threadIdx.x & 3;

    double accd[8][4];
#pragma unroll
    for (int i = 0; i < 8; ++i)
#pragma unroll
        for (int m = 0; m < 4; ++m) accd[i][m] = 0.0;

    const float* w1s = W1 + (size_t)s * 128 * 64 + jg;

    for (int kb = 0; kb < 8; ++kb) {
        float acc[8][4];
#pragma unroll
        for (int i = 0; i < 8; ++i)
#pragma unroll
            for (int m = 0; m < 4; ++m) acc[i][m] = 0.f;
#pragma unroll
        for (int kq = 0; kq < 4; ++kq) {
            int K4 = kb * 4 + kq;
            float4 xv[8];
#pragma unroll
            for (int i = 0; i < 8; ++i)
                xv[i] = *(const float4*)&vt[ng * 8 + i][(K4 ^ ng) << 2];
#pragma unroll
            for (int kk = 0; kk < 4; ++kk) {
                int k = K4 * 4 + kk;
                float w0 = w1s[k * 64 +  0];
                float w1 = w1s[k * 64 + 16];
                float w2 = w1s[k * 64 + 32];
                float w3 = w1s[k * 64 + 48];
#pragma unroll
                for (int i = 0; i < 8; ++i) {
                    float x = (kk == 0) ? xv[i].x : (kk == 1) ? xv[i].y
                            : (kk == 2) ? xv[i].z : xv[i].w;
                    acc[i][0] = fmaf(x, w0, acc[i][0]);
                    acc[i][1] = fmaf(x, w1, acc[i][1]);
                    acc[i][2] = fmaf(x, w2, acc[i][2]);
                    acc[i][3] = fmaf(x, w3, acc[i][3]);
                }
            }
        }
#pragma unroll
        for (int i = 0; i < 8; ++i)
#pragma unroll
            for (int m = 0; m < 4; ++m) accd[i][m] += (double)acc[i][m];
    }

#pragma unroll
    for (int i = 0; i < 8; ++i) {
        int n = nb + ng * 8 + i;
#pragma unroll
        for (int m = 0; m < 4; ++m) {
            int j = jg + 16 * m;
            float pv = (float)accd[i][m];
            P[(size_t)s * NN * 64 + (size_t)n * 64 + j] = pv;
            if (s == 0) {
                base[(size_t)n * 64 + j] = pv + b1[j];
                if (j == 0) walk_idx[n] = n;
            }
        }
    }
}

// ---------------------------------------------------------------------------
// Kernel 2: all 3 walk steps fused, one wave per node. base in registers;
// P[sel] via lane-group broadcast (bit-identical). L2-thrash-bound floor:
// ~102 MB intrinsic random-gather traffic (8-XCD replication of 5.12 MB
// f32 P-slices; cannot shrink without bf16 argmax risk).
// ---------------------------------------------------------------------------
__global__ __launch_bounds__(256) void k_walk_fused(
    const float* __restrict__ P, const float* __restrict__ base_g,
    const int* __restrict__ dst, const float* __restrict__ W2,
    const float* __restrict__ b2, const float* __restrict__ noise,
    int* __restrict__ walk_idx)
{
    int wave = threadIdx.x >> 6;
    int lane = threadIdx.x & 63;
    int n = blockIdx.x * 4 + wave;
    int d = lane >> 2, sub = lane & 3;

    float4 base_r[4], w2r[4];
    {
        const float4* bg = (const float4*)(base_g + (size_t)n * 64 + sub * 16);
        const float4* wg = ((const float4*)W2) + sub * 4;
#pragma unroll
        for (int k = 0; k < 4; ++k) { base_r[k] = bg[k]; w2r[k] = wg[k]; }
    }
    double b2d = (double)b2[0];

    int wl = n;
#pragma unroll 1
    for (int t = 0; t < TSTEPS; ++t) {
        const float* Pslice = P + (size_t)(t + 1) * NN * 64;
        int cand = dst[wl * DEGV + d];
        const float4* p4 = (const float4*)(Pslice + (size_t)cand * 64 + sub * 16);

        float4 pp_s[4];
        double acc = 0.0;
#pragma unroll
        for (int k = 0; k < 4; ++k) {
            float4 bb = base_r[k];
            float4 pp = p4[k];
            pp_s[k] = pp;
            float4 ww = w2r[k];
            acc += (double)fmaxf(bb.x + pp.x, 0.f) * (double)ww.x;
            acc += (double)fmaxf(bb.y + pp.y, 0.f) * (double)ww.y;
            acc += (double)fmaxf(bb.z + pp.z, 0.f) * (double)ww.z;
            acc += (double)fmaxf(bb.w + pp.w, 0.f) * (double)ww.w;
        }
        acc += __shfl_xor(acc, 1);
        acc += __shfl_xor(acc, 2);
        double logp = acc + b2d;

        double m = logp;
        for (int mask = 4; mask < 64; mask <<= 1) m = fmax(m, __shfl_xor(m, mask));
        double e = exp_fast(logp - m);
        double ssum = e;
        for (int mask = 4; mask < 64; mask <<= 1) ssum += __shfl_xor(ssum, mask);

        double wp = e / ssum +
                    0.01 * (double)noise[((size_t)t * NN + n) * DEGV + d];

        int bd = d;
        double bwp = wp;
        for (int mask = 4; mask < 64; mask <<= 1) {
            double owp = __shfl_xor(bwp, mask);
            int od = __shfl_xor(bd, mask);
            if (owp > bwp || (owp == bwp && od < bd)) { bwp = owp; bd = od; }
        }
        int sel = dst[wl * DEGV + bd];

        int srcl = bd * 4 + sub;
#pragma unroll
        for (int k = 0; k < 4; ++k) {
            base_r[k].x += __shfl(pp_s[k].x, srcl);
            base_r[k].y += __shfl(pp_s[k].y, srcl);
            base_r[k].z += __shfl(pp_s[k].z, srcl);
            base_r[k].w += __shfl(pp_s[k].w, srcl);
        }
        if (lane == 0) walk_idx[(t + 1) * NN + n] = sel;
        wl = sel;
    }
}

// ---------------------------------------------------------------------------
// Kernel 3: fused GRU (4 steps) + output projection, MFMA bf16.
// EXACT r9 kernel — (512,4), 64 VGPR, no spill, measured 59.6 us.
// (512,8) in r15 forced VGPR->32 and spilled (99.4 us): do not raise.
// Seven structural variants (r9-r15) all >= 59.6 -> this is the floor of
// this kernel family.
// ---------------------------------------------------------------------------
__global__ __launch_bounds__(512, 4) void k_gru_fused(
    const short* __restrict__ vb, const int* __restrict__ widx,
    const short* __restrict__ Wihb, const short* __restrict__ Whhb,
    const short* __restrict__ WoutTb,
    const float* __restrict__ bih, const float* __restrict__ bhh,
    const float* __restrict__ bout, float* __restrict__ out)
{
    __shared__ short x_bf[32][136];
    __shared__ short h_bf[32][136];
    int tid = threadIdx.x;
    int j = tid >> 6, lane = tid & 63;
    int c = lane & 15, q = lane >> 4;
    int nb = blockIdx.x * 32;
    int u = j * 16 + c;

    float b_r  = bih[u] + bhh[u];
    float b_z  = bih[128 + u] + bhh[128 + u];
    float b_in = bih[256 + u];
    float b_hn = bhh[256 + u];

    float h_reg[2][4];
#pragma unroll
    for (int g = 0; g < 2; ++g)
#pragma unroll
        for (int i = 0; i < 4; ++i) h_reg[g][i] = 0.f;

    const short* bi_base = Wihb + c * 128 + q * 8 + j * 2048;
    const short* bh_base = Whhb + c * 128 + q * 8 + j * 2048;

#pragma unroll 1
    for (int t = 0; t < 1 + TSTEPS; ++t) {
        {
            int row = tid >> 4, chunk = tid & 15;
            int src = widx[t * NN + nb + row];
            *(s16x8*)&x_bf[row][chunk * 8] =
                *(const s16x8*)(vb + (size_t)src * 128 + chunk * 8);
        }
        __syncthreads();

        float rr[2][4], zz[2][4];

        // pass 1: r and z
        {
            f32x4 zf = {0.f, 0.f, 0.f, 0.f};
            f32x4 aR[2] = {zf, zf}, aZ[2] = {zf, zf};
#pragma unroll
            for (int ks = 0; ks < 4; ++ks) {
                s16x8 biR = *(const s16x8*)(bi_base + ks * 32);
                s16x8 biZ = *(const s16x8*)(bi_base + 8 * 2048 + ks * 32);
#pragma unroll
                for (int g = 0; g < 2; ++g) {
                    s16x8 a = *(const s16x8*)&x_bf[g * 16 + c][ks * 32 + q * 8];
                    aR[g] = MFMA16(a, biR, aR[g]);
                    aZ[g] = MFMA16(a, biZ, aZ[g]);
                }
            }
            if (t > 0) {
#pragma unroll
                for (int ks = 0; ks < 4; ++ks) {
                    s16x8 bhR = *(const s16x8*)(bh_base + ks * 32);
                    s16x8 bhZ = *(const s16x8*)(bh_base + 8 * 2048 + ks * 32);
#pragma unroll
                    for (int g = 0; g < 2; ++g) {
                        s16x8 a = *(const s16x8*)&h_bf[g * 16 + c][ks * 32 + q * 8];
                        aR[g] = MFMA16(a, bhR, aR[g]);
                        aZ[g] = MFMA16(a, bhZ, aZ[g]);
                    }
                }
            }
#pragma unroll
            for (int g = 0; g < 2; ++g)
#pragma unroll
                for (int i = 0; i < 4; ++i) {
                    rr[g][i] = 1.f / (1.f + __expf(-(aR[g][i] + b_r)));
                    zz[g][i] = 1.f / (1.f + __expf(-(aZ[g][i] + b_z)));
                }
        }

        // pass 2: in and hn, then epilogue
        {
            f32x4 zf = {0.f, 0.f, 0.f, 0.f};
            f32x4 aIN[2] = {zf, zf}, aHN[2] = {zf, zf};
#pragma unroll
            for (int ks = 0; ks < 4; ++ks) {
                s16x8 biN = *(const s16x8*)(bi_base + 16 * 2048 + ks * 32);
#pragma unroll
                for (int g = 0; g < 2; ++g) {
                    s16x8 a = *(const s16x8*)&x_bf[g * 16 + c][ks * 32 + q * 8];
                    aIN[g] = MFMA16(a, biN, aIN[g]);
                }
            }
            if (t > 0) {
#pragma unroll
                for (int ks = 0; ks < 4; ++ks) {
                    s16x8 bhN = *(const s16x8*)(bh_base + 16 * 2048 + ks * 32);
#pragma unroll
                    for (int g = 0; g < 2; ++g) {
                        s16x8 a = *(const s16x8*)&h_bf[g * 16 + c][ks * 32 + q * 8];
                        aHN[g] = MFMA16(a, bhN, aHN[g]);
                    }
                }
            }
            __syncthreads();
#pragma unroll
            for (int g = 0; g < 2; ++g)
#pragma unroll
                for (int i = 0; i < 4; ++i) {
                    float narg = aIN[g][i] + b_in + rr[g][i] * (aHN[g][i] + b_hn);
                    float e2 = __expf(2.f * narg);
                    float ngt = 1.f - 2.f / (e2 + 1.f);
                    float hn = (1.f - zz[g][i]) * ngt + zz[g][i] * h_reg[g][i];
                    h_reg[g][i] = hn;
                    h_bf[g * 16 + q * 4 + i][u] = f2bf(hn);
                }
        }
        __syncthreads();
    }

    // output projection
    {
        const short* bo_base = WoutTb + c * 128 + q * 8 + j * 2048;
        f32x4 zf = {0.f, 0.f, 0.f, 0.f};
        f32x4 acco[2] = {zf, zf};
#pragma unroll
        for (int ks = 0; ks < 4; ++ks) {
            s16x8 bo = *(const s16x8*)(bo_base + ks * 32);
#pragma unroll
            for (int g = 0; g < 2; ++g) {
                s16x8 a = *(const s16x8*)&h_bf[g * 16 + c][ks * 32 + q * 8];
                acco[g] = MFMA16(a, bo, acco[g]);
            }
        }
        float bb = bout[u];
#pragma unroll
        for (int g = 0; g < 2; ++g)
#pragma unroll
            for (int i = 0; i < 4; ++i)
                out[(size_t)(nb + g * 16 + q * 4 + i) * 128 + u] = acco[g][i] + bb;
    }
}

// ---------------------------------------------------------------------------
extern "C" void kernel_launch(void* const* d_in, const int* in_sizes, int n_in,
                              void* d_out, int out_size, void* d_ws, size_t ws_size,
                              hipStream_t stream)
{
    const float* node_attr = (const float*)d_in[0];
    const int*   edge_index = (const int*)d_in[1];
    const float* W1  = (const float*)d_in[3];
    const float* b1  = (const float*)d_in[4];
    const float* W2  = (const float*)d_in[5];
    const float* b2  = (const float*)d_in[6];
    const float* Wih = (const float*)d_in[7];
    const float* Whh = (const float*)d_in[8];
    const float* bih = (const float*)d_in[9];
    const float* bhh = (const float*)d_in[10];
    const float* Wout = (const float*)d_in[11];
    const float* bout = (const float*)d_in[12];
    const float* noise = (const float*)d_in[13];

    const int* dst = edge_index + (size_t)NN * DEGV;

    char* ws = (char*)d_ws;
    size_t offP    = 0;                               // 4*N*64 f32 = 20.48 MB
    size_t offBase = offP + (size_t)4 * NN * 64 * 4;  // N*64 f32   =  5.12 MB
    size_t offW    = offBase + (size_t)NN * 64 * 4;   // bf16 weights 0.23 MB
    size_t offWidx = offW + (size_t)(2 * 49152 + 16384) * 2;
    size_t offVb   = offWidx + (size_t)4 * NN * 4;    // bf16 v = 5.12 MB
    float* P    = (float*)(ws + offP);
    float* base = (float*)(ws + offBase);
    short* Wihb   = (short*)(ws + offW);
    short* Whhb   = Wihb + 384 * 128;
    short* WoutTb = Whhb + 384 * 128;
    int*   widx = (int*)(ws + offWidx);
    short* vb   = (short*)(ws + offVb);

    dim3 blk(256);
    k_precompute<<<dim3(625), blk, 0, stream>>>(node_attr, W1, b1, Wih, Whh, Wout,
                                                P, base, widx, vb, Wihb, Whhb, WoutTb);
    k_walk_fused<<<dim3(5000), blk, 0, stream>>>(P, base, dst, W2, b2, noise, widx);
    k_gru_fused<<<dim3(625), dim3(512), 0, stream>>>(vb, widx, Wihb, Whhb, WoutTb,
                                                     bih, bhh, bout, (float*)d_out);
}